// Round 13
// baseline (471.261 us; speedup 1.0000x reference)
//
#include <hip/hip_runtime.h>
#include <hip/hip_bf16.h>

typedef short bf16x8 __attribute__((ext_vector_type(8)));
typedef float f32x4  __attribute__((ext_vector_type(4)));
typedef unsigned short u16;
typedef unsigned int u32;

// ---- LDS: W frag-image 48KB + 4 pairs x 6KB scratch = 72KB (2 blocks/CU) ----
#define LDS_W     0u
#define LDS_SCR   49152u
#define LDS_BYTES 73728u

// ---- workspace ----
#define WS_QKVW 0u          // 8 heads x 48 frags x 1KB  (frag = (ct*8+ks)*1024 + lane*16)
#define WS_OUTW 393216u     // 128 frags x 1KB = 4 chunks x 32KB
#define WS_QB   524288u     // [8][96] f32

// mask rows (bits 0..25); rows 26..31 dummy bit0 keeps pad rows finite
__constant__ u32 MASK32[32] = {
  0x0210000Fu,0x0210000Fu,0x0210000Fu,0x0210000Fu,
  0x026000F0u,0x026000F0u,0x026000F0u,0x026000F0u,
  0x03800F00u,0x03800F00u,0x03800F00u,0x03800F00u,
  0x0200F000u,0x0200F000u,0x0200F000u,0x0200F000u,
  0x020F0000u,0x020F0000u,0x020F0000u,0x020F0000u,
  0x0210000Fu,
  0x026000F0u,0x026000F0u,
  0x03800F00u,0x03800F00u,
  0x03FFFFFFu,
  0x1u,0x1u,0x1u,0x1u,0x1u,0x1u
};

// packed f32x2 -> bf16x2 (RNE) via native cvt
__device__ __forceinline__ u32 pk2(float a, float b) {
  float2 f; f.x = a; f.y = b;
  __hip_bfloat162 h = __float22bfloat162_rn(f);
  union { __hip_bfloat162 h; u32 u; } c; c.h = h; return c.u;
}
__device__ __forceinline__ uint2 pk4(float a, float b, float c, float d) {
  uint2 r; r.x = pk2(a, b); r.y = pk2(c, d); return r;
}
// bijective 64B-row swizzle: XOR on the FULL byte offset (round-3-verified)
__device__ __forceinline__ u32 sw64(int row, int col2) {
  return (u32)((row * 64 + col2) ^ ((row & 7) << 4));
}
// async global->LDS, 16B per lane; LDS dest = uniform base + lane*16 (HW rule)
__device__ __forceinline__ void gll16(const void* g, void* l) {
  __builtin_amdgcn_global_load_lds(
      (const __attribute__((address_space(1))) void*)g,
      (__attribute__((address_space(3))) void*)l, 16, 0, 0);
}

// ---- prep: fragment-order bf16 weight images + packed bias ----
__global__ __launch_bounds__(256)
void prep(const float* __restrict__ qkv_w, const float* __restrict__ qkv_b,
          const float* __restrict__ out_w, unsigned char* __restrict__ ws)
{
  int t = blockIdx.x * 256 + threadIdx.x;
  if (t < 24576) {                       // qkv frags: 8h x 48fr x 64 lanes
    int h = t / 3072, rem = t - h * 3072;
    int fr = rem >> 6, ln = rem & 63;
    int ct = fr >> 3, ks = fr & 7;
    int lr = ln & 15, lg = ln >> 4;
    int fg = (ct >> 1) * 256 + h * 32 + (ct & 1) * 16 + lr;
    const float* s = qkv_w + fg * 256 + ks * 32 + lg * 8;
    float4 v0 = *(const float4*)s, v1 = *(const float4*)(s + 4);
    uint4 o;
    o.x = pk2(v0.x, v0.y); o.y = pk2(v0.z, v0.w);
    o.z = pk2(v1.x, v1.y); o.w = pk2(v1.z, v1.w);
    *(uint4*)(ws + WS_QKVW + (u32)h * 49152u + (u32)fr * 1024u + (u32)ln * 16u) = o;
  } else if (t < 32768) {                // outw frags: 128fr x 64 lanes
    int g = t - 24576;
    int fr = g >> 6, ln = g & 63;
    int ft = fr >> 3, ks = fr & 7;
    int lr = ln & 15, lg = ln >> 4;
    const float* s = out_w + (ft * 16 + lr) * 256 + ks * 32 + lg * 8;
    float4 v0 = *(const float4*)s, v1 = *(const float4*)(s + 4);
    uint4 o;
    o.x = pk2(v0.x, v0.y); o.y = pk2(v0.z, v0.w);
    o.z = pk2(v1.x, v1.y); o.w = pk2(v1.z, v1.w);
    *(uint4*)(ws + WS_OUTW + (u32)fr * 1024u + (u32)ln * 16u) = o;
  } else if (t < 33536) {                // qkv bias [8][96]
    int i = t - 32768;
    int h = i / 96, j = i - h * 96;
    int ct = j >> 4, lr = j & 15;
    ((float*)(ws + WS_QB))[i] = qkv_b[(ct >> 1) * 256 + h * 32 + (ct & 1) * 16 + lr];
  }
}

// 512 threads, 4 waves/EU (128-reg tier), 2 blocks/CU = 16 waves/CU.
__global__ __launch_bounds__(512, 4)
void brain_fused(const float* __restrict__ x,
                 const unsigned char* __restrict__ ws,
                 const float* __restrict__ out_b,
                 float* __restrict__ out)
{
  __shared__ char smem[LDS_BYTES] __attribute__((aligned(16)));
  const int tid  = threadIdx.x;
  const int lane = tid & 63;
  const int wid  = tid >> 6;          // 0..7
  const int half = wid & 1;           // 16-row half of the batch
  const int pair = wid >> 1;          // 0..3 = batch within block
  const int lr   = lane & 15;
  const int lg   = lane >> 4;
  const size_t rb = (size_t)blockIdx.x * 104 + (size_t)pair * 26;
  const f32x4 zero = {0.f, 0.f, 0.f, 0.f};
  const u32 pb = LDS_SCR + (u32)pair * 6144u;
  const u32 ob = pb + (u32)half * 1024u;  // own q/P'/ctx' [16][32] bf16
  const u32 kb = pb + 2048u;              // shared k  [32][32]
  const u32 vb = pb + 4096u;              // shared v' [32][32] ([d][s])

  // ---- x A-fragments: this wave's 16 rows; pad rows (>=26) = 0 ----
  const int srow = half * 16 + lr;
  bf16x8 af[8];
  {
    const float* xp = x + (rb + (size_t)srow) * 256;
#pragma unroll
    for (int ks = 0; ks < 8; ++ks) {
      if (srow < 26) {
        const float* p = xp + ks * 32 + lg * 8;
        float4 v0 = *(const float4*)p, v1 = *(const float4*)(p + 4);
        union { u32 u[4]; bf16x8 v; } tt;
        tt.u[0] = pk2(v0.x, v0.y); tt.u[1] = pk2(v0.z, v0.w);
        tt.u[2] = pk2(v1.x, v1.y); tt.u[3] = pk2(v1.z, v1.w);
        af[ks] = tt.v;
      } else {
        af[ks] = (bf16x8)(short)0;
      }
    }
  }

  const u32 mq = MASK32[srow];        // mask for q column = srow
  const float* qb = (const float*)(ws + WS_QB);

  // ---- pre-stage W(0): async, 6 granules/wave ----
#pragma unroll
  for (int i = 0; i < 6; ++i) {
    u32 off = (u32)(wid * 6 + i) * 1024u;
    gll16(ws + WS_QKVW + off + (u32)lane * 16u, smem + LDS_W + off);
  }
  __syncthreads();  // drains vmcnt -> W(0) ready

  bf16x8 cf[8];                       // ctx frags (A-operand of out-proj)

#pragma unroll
  for (int h = 0; h < 8; ++h) {
    // ---- QKV single pass: 6 independent acc chains, 48 MFMAs back-to-back ----
    f32x4 acc[6];
#pragma unroll
    for (int ct = 0; ct < 6; ++ct) {
      float bb = qb[h * 96 + ct * 16 + lr];
      f32x4 bv = {bb, bb, bb, bb};
      acc[ct] = bv;
    }
    __builtin_amdgcn_s_setprio(1);
#pragma unroll
    for (int ks = 0; ks < 8; ++ks) {
      // two groups of 3 B-frags: 6 MFMA chains' worth of ILP, 12-reg transient
#pragma unroll
      for (int g = 0; g < 2; ++g) {
        bf16x8 bw[3];
#pragma unroll
        for (int c = 0; c < 3; ++c)
          bw[c] = *(const bf16x8*)(smem + LDS_W + (u32)(((g * 3 + c) * 8 + ks) << 10) + (u32)lane * 16u);
#pragma unroll
        for (int c = 0; c < 3; ++c)
          acc[g * 3 + c] =
              __builtin_amdgcn_mfma_f32_16x16x32_bf16(af[ks], bw[c], acc[g * 3 + c], 0, 0, 0);
      }
    }
    __builtin_amdgcn_s_setprio(0);

    // ---- scratch writes: q(acc0,1) -> ob, k(acc2,3) -> kb, v'(acc4,5) -> vb ----
#pragma unroll
    for (int r = 0; r < 4; ++r) {
      u32 wq = pk2(acc[0][r], acc[1][r]);
      int sq = lg * 4 + r;
      *(u16*)(smem + ob + sw64(sq, lr * 2)) = (u16)wq;
      *(u16*)(smem + ob + sw64(sq, (16 + lr) * 2)) = (u16)(wq >> 16);
      u32 wk = pk2(acc[2][r], acc[3][r]);
      int sk = half * 16 + lg * 4 + r;
      *(u16*)(smem + kb + sw64(sk, lr * 2)) = (u16)wk;
      *(u16*)(smem + kb + sw64(sk, (16 + lr) * 2)) = (u16)(wk >> 16);
    }
#pragma unroll
    for (int c = 0; c < 2; ++c)
      *(uint2*)(smem + vb + sw64(c * 16 + lr, (half * 16 + lg * 4) * 2)) =
          pk4(acc[4 + c][0], acc[4 + c][1], acc[4 + c][2], acc[4 + c][3]);
    __syncthreads();  // b2: pair k/v' visible AND all waves done reading W(h)

    // ---- async stage of next LDS image overlaps the attention below ----
    if (h < 7) {
      const unsigned char* nsrc = ws + WS_QKVW + (u32)(h + 1) * 49152u;
#pragma unroll
      for (int i = 0; i < 6; ++i) {
        u32 off = (u32)(wid * 6 + i) * 1024u;
        gll16(nsrc + off + (u32)lane * 16u, smem + LDS_W + off);
      }
    } else {
#pragma unroll
      for (int i = 0; i < 4; ++i) {
        u32 off = (u32)(wid * 4 + i) * 1024u;
        gll16(ws + WS_OUTW + off + (u32)lane * 16u, smem + LDS_W + off);
      }
    }

    // ---- QK^T: sc = K(32) x Q(own 16) ----
    bf16x8 qf = *(const bf16x8*)(smem + ob + sw64(lr, lg * 16));
    bf16x8 kf[2];
#pragma unroll
    for (int t = 0; t < 2; ++t)
      kf[t] = *(const bf16x8*)(smem + kb + sw64(t * 16 + lr, lg * 16));
    f32x4 sc[2];
    __builtin_amdgcn_s_setprio(1);
#pragma unroll
    for (int st = 0; st < 2; ++st)
      sc[st] = __builtin_amdgcn_mfma_f32_16x16x32_bf16(kf[st], qf, zero, 0, 0, 0);
    __builtin_amdgcn_s_setprio(0);

    // ---- masked softmax (q col = srow), P'[q_loc][s_k] packed b64 ----
    {
      float mx = -3.0e38f;
#pragma unroll
      for (int st = 0; st < 2; ++st)
#pragma unroll
        for (int r = 0; r < 4; ++r) {
          int sk = st * 16 + lg * 4 + r;
          if ((mq >> sk) & 1u) mx = fmaxf(mx, sc[st][r]);
        }
      mx = fmaxf(mx, __shfl_xor(mx, 16));
      mx = fmaxf(mx, __shfl_xor(mx, 32));
      float pex[2][4];
      float sum = 0.f;
#pragma unroll
      for (int st = 0; st < 2; ++st)
#pragma unroll
        for (int r = 0; r < 4; ++r) {
          int sk = st * 16 + lg * 4 + r;
          // exp(s/sqrt(32)) = exp2(s * log2(e)/sqrt(32))
          float p = ((mq >> sk) & 1u) ? exp2f((sc[st][r] - mx) * 0.25505277f) : 0.f;
          pex[st][r] = p; sum += p;
        }
      sum += __shfl_xor(sum, 16);
      sum += __shfl_xor(sum, 32);
      float ri = __builtin_amdgcn_rcpf(sum);
#pragma unroll
      for (int st = 0; st < 2; ++st)
        *(uint2*)(smem + ob + sw64(lr, (st * 16 + lg * 4) * 2)) =
            pk4(pex[st][0] * ri, pex[st][1] * ri, pex[st][2] * ri, pex[st][3] * ri);
    }

    // ---- PV: ctx^T = V'(32d) x P'(own 16q) ----
    bf16x8 vf[2];
#pragma unroll
    for (int t = 0; t < 2; ++t)
      vf[t] = *(const bf16x8*)(smem + vb + sw64(t * 16 + lr, lg * 16));
    bf16x8 pf = *(const bf16x8*)(smem + ob + sw64(lr, lg * 16));
    f32x4 pv[2];
    __builtin_amdgcn_s_setprio(1);
#pragma unroll
    for (int dt = 0; dt < 2; ++dt)
      pv[dt] = __builtin_amdgcn_mfma_f32_16x16x32_bf16(vf[dt], pf, zero, 0, 0, 0);
    __builtin_amdgcn_s_setprio(0);

    // ctx'[q_loc][d] packed b64, then read ctx frag
#pragma unroll
    for (int dt = 0; dt < 2; ++dt)
      *(uint2*)(smem + ob + sw64(lr, (dt * 16 + lg * 4) * 2)) =
          pk4(pv[dt][0], pv[dt][1], pv[dt][2], pv[dt][3]);
    cf[h] = *(const bf16x8*)(smem + ob + sw64(lr, lg * 16));

    __syncthreads();  // b3: drains staging vmcnt; scratch free for next head
  } // heads

  // ---- out-projection: 4 chunks of 64 cols; chunk 0 already in LDS ----
#pragma unroll
  for (int fc = 0; fc < 4; ++fc) {
    f32x4 oa[4];
#pragma unroll
    for (int j = 0; j < 4; ++j) {
      float bo = out_b[(fc * 4 + j) * 16 + lr];
      f32x4 bv = {bo, bo, bo, bo};
      oa[j] = bv;
    }
    __builtin_amdgcn_s_setprio(1);
#pragma unroll
    for (int ks = 0; ks < 8; ++ks) {
      bf16x8 bw[4];
#pragma unroll
      for (int j = 0; j < 4; ++j)
        bw[j] = *(const bf16x8*)(smem + LDS_W + (u32)((j * 8 + ks) << 10) + (u32)lane * 16u);
#pragma unroll
      for (int j = 0; j < 4; ++j)
        oa[j] = __builtin_amdgcn_mfma_f32_16x16x32_bf16(cf[ks], bw[j], oa[j], 0, 0, 0);
    }
    __builtin_amdgcn_s_setprio(0);
#pragma unroll
    for (int j = 0; j < 4; ++j)
#pragma unroll
      for (int r = 0; r < 4; ++r) {
        int qrow = half * 16 + lg * 4 + r;
        if (qrow < 26)
          out[(rb + (size_t)qrow) * 256 + (fc * 4 + j) * 16 + lr] = oa[j][r];
      }
    if (fc < 3) {
      __syncthreads();  // all waves done reading chunk fc
#pragma unroll
      for (int i = 0; i < 4; ++i) {
        u32 off = (u32)(wid * 4 + i) * 1024u;
        gll16(ws + WS_OUTW + (u32)(fc + 1) * 32768u + off + (u32)lane * 16u,
              smem + LDS_W + off);
      }
      __syncthreads();  // chunk fc+1 ready (vmcnt drained)
    }
  }
}

extern "C" void kernel_launch(void* const* d_in, const int* in_sizes, int n_in,
                              void* d_out, int out_size, void* d_ws, size_t ws_size,
                              hipStream_t stream) {
  (void)in_sizes; (void)n_in; (void)out_size; (void)ws_size;
  const float* x     = (const float*)d_in[0];
  const float* qkv_w = (const float*)d_in[1];
  const float* qkv_b = (const float*)d_in[2];
  const float* out_w = (const float*)d_in[3];
  const float* out_b = (const float*)d_in[4];
  unsigned char* ws = (unsigned char*)d_ws;
  float* out = (float*)d_out;

  prep<<<dim3(131), dim3(256), 0, stream>>>(qkv_w, qkv_b, out_w, ws);
  brain_fused<<<dim3(4096), dim3(512), 0, stream>>>(x, ws, out_b, out);
}

// Round 14
// 434.721 us; speedup vs baseline: 1.0841x; 1.0841x over previous
//
#include <hip/hip_runtime.h>
#include <hip/hip_bf16.h>

typedef short bf16x8 __attribute__((ext_vector_type(8)));
typedef float f32x4  __attribute__((ext_vector_type(4)));
typedef unsigned short u16;
typedef unsigned int u32;

// ---- LDS: W frag-image 48KB + 4 pairs x 6KB scratch = 72KB (2 blocks/CU) ----
// out-proj reuses [0,32K) and [32K,64K) as a double buffer (scratch dead then).
#define LDS_W     0u
#define LDS_SCR   49152u
#define LDS_BYTES 73728u

// ---- workspace ----
#define WS_QKVW 0u          // 8 heads x 48 frags x 1KB  (frag = (ct*8+ks)*1024 + lane*16)
#define WS_OUTW 393216u     // 128 frags x 1KB = 4 chunks x 32KB
#define WS_QB   524288u     // [8][96] f32

// mask rows (bits 0..25); rows 26..31 dummy bit0 keeps pad rows finite
__constant__ u32 MASK32[32] = {
  0x0210000Fu,0x0210000Fu,0x0210000Fu,0x0210000Fu,
  0x026000F0u,0x026000F0u,0x026000F0u,0x026000F0u,
  0x03800F00u,0x03800F00u,0x03800F00u,0x03800F00u,
  0x0200F000u,0x0200F000u,0x0200F000u,0x0200F000u,
  0x020F0000u,0x020F0000u,0x020F0000u,0x020F0000u,
  0x0210000Fu,
  0x026000F0u,0x026000F0u,
  0x03800F00u,0x03800F00u,
  0x03FFFFFFu,
  0x1u,0x1u,0x1u,0x1u,0x1u,0x1u
};

// packed f32x2 -> bf16x2 (RNE) via native cvt
__device__ __forceinline__ u32 pk2(float a, float b) {
  float2 f; f.x = a; f.y = b;
  __hip_bfloat162 h = __float22bfloat162_rn(f);
  union { __hip_bfloat162 h; u32 u; } c; c.h = h; return c.u;
}
__device__ __forceinline__ uint2 pk4(float a, float b, float c, float d) {
  uint2 r; r.x = pk2(a, b); r.y = pk2(c, d); return r;
}
// bijective 64B-row swizzle: XOR on the FULL byte offset (round-3-verified)
__device__ __forceinline__ u32 sw64(int row, int col2) {
  return (u32)((row * 64 + col2) ^ ((row & 7) << 4));
}
// async global->LDS, 16B per lane; LDS dest = uniform base + lane*16 (HW rule)
__device__ __forceinline__ void gll16(const void* g, void* l) {
  __builtin_amdgcn_global_load_lds(
      (const __attribute__((address_space(1))) void*)g,
      (__attribute__((address_space(3))) void*)l, 16, 0, 0);
}

// ---- prep: fragment-order bf16 weight images + packed bias ----
__global__ __launch_bounds__(256)
void prep(const float* __restrict__ qkv_w, const float* __restrict__ qkv_b,
          const float* __restrict__ out_w, unsigned char* __restrict__ ws)
{
  int t = blockIdx.x * 256 + threadIdx.x;
  if (t < 24576) {                       // qkv frags: 8h x 48fr x 64 lanes
    int h = t / 3072, rem = t - h * 3072;
    int fr = rem >> 6, ln = rem & 63;
    int ct = fr >> 3, ks = fr & 7;
    int lr = ln & 15, lg = ln >> 4;
    int fg = (ct >> 1) * 256 + h * 32 + (ct & 1) * 16 + lr;
    const float* s = qkv_w + fg * 256 + ks * 32 + lg * 8;
    float4 v0 = *(const float4*)s, v1 = *(const float4*)(s + 4);
    uint4 o;
    o.x = pk2(v0.x, v0.y); o.y = pk2(v0.z, v0.w);
    o.z = pk2(v1.x, v1.y); o.w = pk2(v1.z, v1.w);
    *(uint4*)(ws + WS_QKVW + (u32)h * 49152u + (u32)fr * 1024u + (u32)ln * 16u) = o;
  } else if (t < 32768) {                // outw frags: 128fr x 64 lanes
    int g = t - 24576;
    int fr = g >> 6, ln = g & 63;
    int ft = fr >> 3, ks = fr & 7;
    int lr = ln & 15, lg = ln >> 4;
    const float* s = out_w + (ft * 16 + lr) * 256 + ks * 32 + lg * 8;
    float4 v0 = *(const float4*)s, v1 = *(const float4*)(s + 4);
    uint4 o;
    o.x = pk2(v0.x, v0.y); o.y = pk2(v0.z, v0.w);
    o.z = pk2(v1.x, v1.y); o.w = pk2(v1.z, v1.w);
    *(uint4*)(ws + WS_OUTW + (u32)fr * 1024u + (u32)ln * 16u) = o;
  } else if (t < 33536) {                // qkv bias [8][96]
    int i = t - 32768;
    int h = i / 96, j = i - h * 96;
    int ct = j >> 4, lr = j & 15;
    ((float*)(ws + WS_QB))[i] = qkv_b[(ct >> 1) * 256 + h * 32 + (ct & 1) * 16 + lr];
  }
}

// 512 threads, 4 waves/EU (128-reg tier), 2 blocks/CU = 16 waves/CU.
__global__ __launch_bounds__(512, 4)
void brain_fused(const float* __restrict__ x,
                 const unsigned char* __restrict__ ws,
                 const float* __restrict__ out_b,
                 float* __restrict__ out)
{
  __shared__ char smem[LDS_BYTES] __attribute__((aligned(16)));
  const int tid  = threadIdx.x;
  const int lane = tid & 63;
  const int wid  = tid >> 6;          // 0..7
  const int half = wid & 1;           // 16-row half of the batch
  const int pair = wid >> 1;          // 0..3 = batch within block
  const int lr   = lane & 15;
  const int lg   = lane >> 4;
  const size_t rb = (size_t)blockIdx.x * 104 + (size_t)pair * 26;
  const f32x4 zero = {0.f, 0.f, 0.f, 0.f};
  const u32 pb = LDS_SCR + (u32)pair * 6144u;
  const u32 ob = pb + (u32)half * 1024u;  // own q/P'/ctx' [16][32] bf16
  const u32 kb = pb + 2048u;              // shared k  [32][32]
  const u32 vb = pb + 4096u;              // shared v' [32][32] ([d][s])

  // ---- x A-fragments: this wave's 16 rows; pad rows (>=26) = 0 ----
  const int srow = half * 16 + lr;
  bf16x8 af[8];
  {
    const float* xp = x + (rb + (size_t)srow) * 256;
#pragma unroll
    for (int ks = 0; ks < 8; ++ks) {
      if (srow < 26) {
        const float* p = xp + ks * 32 + lg * 8;
        float4 v0 = *(const float4*)p, v1 = *(const float4*)(p + 4);
        union { u32 u[4]; bf16x8 v; } tt;
        tt.u[0] = pk2(v0.x, v0.y); tt.u[1] = pk2(v0.z, v0.w);
        tt.u[2] = pk2(v1.x, v1.y); tt.u[3] = pk2(v1.z, v1.w);
        af[ks] = tt.v;
      } else {
        af[ks] = (bf16x8)(short)0;
      }
    }
  }

  const u32 mq = MASK32[srow];        // mask for q column = srow
  const float* qb = (const float*)(ws + WS_QB);

  // ---- pre-stage W(0): async, 6 granules/wave ----
#pragma unroll
  for (int i = 0; i < 6; ++i) {
    u32 off = (u32)(wid * 6 + i) * 1024u;
    gll16(ws + WS_QKVW + off + (u32)lane * 16u, smem + LDS_W + off);
  }
  __syncthreads();  // drains vmcnt -> W(0) ready

  bf16x8 cf[8];                       // ctx frags (A-operand of out-proj)

#pragma unroll
  for (int h = 0; h < 8; ++h) {
    // ---- QKV in 3 passes (q, k, v'): 16 rows x 32 feats each, K=256 ----
    // q/k use d-interleaved layout: pos(d) = (d&15)*4 + (d>>4)*2 bytes.
    // Same K-permutation on q and k => QK^T invariant; single b32 write/pair.
#pragma unroll
    for (int p = 0; p < 3; ++p) {
      f32x4 acc[2];
#pragma unroll
      for (int c = 0; c < 2; ++c) {
        float bb = qb[h * 96 + (p * 2 + c) * 16 + lr];
        f32x4 bv = {bb, bb, bb, bb};
        acc[c] = bv;
      }
      __builtin_amdgcn_s_setprio(1);
#pragma unroll
      for (int ks = 0; ks < 8; ++ks) {
        bf16x8 bw[2];
#pragma unroll
        for (int c = 0; c < 2; ++c)
          bw[c] = *(const bf16x8*)(smem + LDS_W + (u32)(((p * 2 + c) * 8 + ks) << 10) + (u32)lane * 16u);
#pragma unroll
        for (int c = 0; c < 2; ++c)
          acc[c] = __builtin_amdgcn_mfma_f32_16x16x32_bf16(af[ks], bw[c], acc[c], 0, 0, 0);
      }
      __builtin_amdgcn_s_setprio(0);
      // per-pass scratch write
      if (p == 0) {
#pragma unroll
        for (int r = 0; r < 4; ++r)
          *(u32*)(smem + ob + sw64(lg * 4 + r, lr * 4)) = pk2(acc[0][r], acc[1][r]);
      } else if (p == 1) {
#pragma unroll
        for (int r = 0; r < 4; ++r)
          *(u32*)(smem + kb + sw64(half * 16 + lg * 4 + r, lr * 4)) = pk2(acc[0][r], acc[1][r]);
      } else {
#pragma unroll
        for (int c = 0; c < 2; ++c)
          *(uint2*)(smem + vb + sw64(c * 16 + lr, (half * 16 + lg * 4) * 2)) =
              pk4(acc[c][0], acc[c][1], acc[c][2], acc[c][3]);
      }
    }
    __syncthreads();  // b2: pair k/v' visible AND all waves done reading W(h)

    // ---- async stage of next LDS image overlaps the attention below ----
    if (h < 7) {
      const unsigned char* nsrc = ws + WS_QKVW + (u32)(h + 1) * 49152u;
#pragma unroll
      for (int i = 0; i < 6; ++i) {
        u32 off = (u32)(wid * 6 + i) * 1024u;
        gll16(nsrc + off + (u32)lane * 16u, smem + LDS_W + off);
      }
    } else {
      // out-proj chunk 0 -> buf0 [0,32K)
#pragma unroll
      for (int i = 0; i < 4; ++i) {
        u32 off = (u32)(wid * 4 + i) * 1024u;
        gll16(ws + WS_OUTW + off + (u32)lane * 16u, smem + off);
      }
    }

    // ---- QK^T: sc = K(32) x Q(own 16); both frags read the interleaved d ----
    bf16x8 qf = *(const bf16x8*)(smem + ob + sw64(lr, lg * 16));
    bf16x8 kf[2];
#pragma unroll
    for (int t = 0; t < 2; ++t)
      kf[t] = *(const bf16x8*)(smem + kb + sw64(t * 16 + lr, lg * 16));
    f32x4 sc[2];
    __builtin_amdgcn_s_setprio(1);
#pragma unroll
    for (int st = 0; st < 2; ++st)
      sc[st] = __builtin_amdgcn_mfma_f32_16x16x32_bf16(kf[st], qf, zero, 0, 0, 0);
    __builtin_amdgcn_s_setprio(0);

    // ---- masked softmax (q col = srow), P'[q_loc][s_k] packed b64 ----
    {
      float mx = -3.0e38f;
#pragma unroll
      for (int st = 0; st < 2; ++st)
#pragma unroll
        for (int r = 0; r < 4; ++r) {
          int sk = st * 16 + lg * 4 + r;
          if ((mq >> sk) & 1u) mx = fmaxf(mx, sc[st][r]);
        }
      mx = fmaxf(mx, __shfl_xor(mx, 16));
      mx = fmaxf(mx, __shfl_xor(mx, 32));
      float pex[2][4];
      float sum = 0.f;
#pragma unroll
      for (int st = 0; st < 2; ++st)
#pragma unroll
        for (int r = 0; r < 4; ++r) {
          int sk = st * 16 + lg * 4 + r;
          // exp(s/sqrt(32)) = exp2(s * log2(e)/sqrt(32))
          float p = ((mq >> sk) & 1u) ? exp2f((sc[st][r] - mx) * 0.25505277f) : 0.f;
          pex[st][r] = p; sum += p;
        }
      sum += __shfl_xor(sum, 16);
      sum += __shfl_xor(sum, 32);
      float ri = __builtin_amdgcn_rcpf(sum);
#pragma unroll
      for (int st = 0; st < 2; ++st)
        *(uint2*)(smem + ob + sw64(lr, (st * 16 + lg * 4) * 2)) =
            pk4(pex[st][0] * ri, pex[st][1] * ri, pex[st][2] * ri, pex[st][3] * ri);
    }

    // ---- PV: ctx^T = V'(32d) x P'(own 16q) ----
    bf16x8 vf[2];
#pragma unroll
    for (int t = 0; t < 2; ++t)
      vf[t] = *(const bf16x8*)(smem + vb + sw64(t * 16 + lr, lg * 16));
    bf16x8 pf = *(const bf16x8*)(smem + ob + sw64(lr, lg * 16));
    f32x4 pv[2];
    __builtin_amdgcn_s_setprio(1);
#pragma unroll
    for (int dt = 0; dt < 2; ++dt)
      pv[dt] = __builtin_amdgcn_mfma_f32_16x16x32_bf16(vf[dt], pf, zero, 0, 0, 0);
    __builtin_amdgcn_s_setprio(0);

    // ctx'[q_loc][d] packed b64, then read ctx frag
#pragma unroll
    for (int dt = 0; dt < 2; ++dt)
      *(uint2*)(smem + ob + sw64(lr, (dt * 16 + lg * 4) * 2)) =
          pk4(pv[dt][0], pv[dt][1], pv[dt][2], pv[dt][3]);
    cf[h] = *(const bf16x8*)(smem + ob + sw64(lr, lg * 16));

    __syncthreads();  // b3: drains staging vmcnt; scratch free for next head
  } // heads

  // ---- out-projection: 4 chunks of 64 cols, LDS double-buffered ----
  // buf0 = [0,32K), buf1 = [32K,64K) (old W tail + scratch; dead after b3).
  // 1 barrier per chunk; next-chunk gll16 overlaps current MFMAs.
#pragma unroll
  for (int fc = 0; fc < 4; ++fc) {
    const u32 cur = (fc & 1) ? 32768u : 0u;
    if (fc < 3) {
      const u32 nxt = ((fc + 1) & 1) ? 32768u : 0u;
#pragma unroll
      for (int i = 0; i < 4; ++i) {
        u32 off = (u32)(wid * 4 + i) * 1024u;
        gll16(ws + WS_OUTW + (u32)(fc + 1) * 32768u + off + (u32)lane * 16u,
              smem + nxt + off);
      }
    }
    f32x4 oa[4];
#pragma unroll
    for (int j = 0; j < 4; ++j) {
      float bo = out_b[(fc * 4 + j) * 16 + lr];
      f32x4 bv = {bo, bo, bo, bo};
      oa[j] = bv;
    }
    __builtin_amdgcn_s_setprio(1);
#pragma unroll
    for (int ks = 0; ks < 8; ++ks) {
      bf16x8 bw[4];
#pragma unroll
      for (int j = 0; j < 4; ++j)
        bw[j] = *(const bf16x8*)(smem + cur + (u32)((j * 8 + ks) << 10) + (u32)lane * 16u);
#pragma unroll
      for (int j = 0; j < 4; ++j)
        oa[j] = __builtin_amdgcn_mfma_f32_16x16x32_bf16(cf[ks], bw[j], oa[j], 0, 0, 0);
    }
    __builtin_amdgcn_s_setprio(0);
#pragma unroll
    for (int j = 0; j < 4; ++j)
#pragma unroll
      for (int r = 0; r < 4; ++r) {
        int qrow = half * 16 + lg * 4 + r;
        if (qrow < 26)
          out[(rb + (size_t)qrow) * 256 + (fc * 4 + j) * 16 + lr] = oa[j][r];
      }
    if (fc < 3)
      __syncthreads();  // drains next-chunk gll16; all waves done with cur
  }
}

extern "C" void kernel_launch(void* const* d_in, const int* in_sizes, int n_in,
                              void* d_out, int out_size, void* d_ws, size_t ws_size,
                              hipStream_t stream) {
  (void)in_sizes; (void)n_in; (void)out_size; (void)ws_size;
  const float* x     = (const float*)d_in[0];
  const float* qkv_w = (const float*)d_in[1];
  const float* qkv_b = (const float*)d_in[2];
  const float* out_w = (const float*)d_in[3];
  const float* out_b = (const float*)d_in[4];
  unsigned char* ws = (unsigned char*)d_ws;
  float* out = (float*)d_out;

  prep<<<dim3(131), dim3(256), 0, stream>>>(qkv_w, qkv_b, out_w, ws);
  brain_fused<<<dim3(4096), dim3(512), 0, stream>>>(x, ws, out_b, out);
}

// Round 15
// 422.760 us; speedup vs baseline: 1.1147x; 1.0283x over previous
//
#include <hip/hip_runtime.h>
#include <hip/hip_bf16.h>

typedef short bf16x8 __attribute__((ext_vector_type(8)));
typedef float f32x4  __attribute__((ext_vector_type(4)));
typedef unsigned short u16;
typedef unsigned int u32;

// ---- LDS: W frag-image 48KB + 4 pairs x 6KB scratch = 72KB (2 blocks/CU) ----
// out-proj reuses [0,32K) and [32K,64K) as a double buffer (scratch dead then).
#define LDS_W     0u
#define LDS_SCR   49152u
#define LDS_BYTES 73728u

// ---- workspace ----
#define WS_QKVW 0u          // 8 heads x 48 frags x 1KB  (frag = (ct*8+ks)*1024 + lane*16)
#define WS_OUTW 393216u     // 128 frags x 1KB = 4 chunks x 32KB
#define WS_QB   524288u     // [8][96] f32

// mask rows (bits 0..25); rows 26..31 dummy bit0 keeps pad rows finite
__constant__ u32 MASK32[32] = {
  0x0210000Fu,0x0210000Fu,0x0210000Fu,0x0210000Fu,
  0x026000F0u,0x026000F0u,0x026000F0u,0x026000F0u,
  0x03800F00u,0x03800F00u,0x03800F00u,0x03800F00u,
  0x0200F000u,0x0200F000u,0x0200F000u,0x0200F000u,
  0x020F0000u,0x020F0000u,0x020F0000u,0x020F0000u,
  0x0210000Fu,
  0x026000F0u,0x026000F0u,
  0x03800F00u,0x03800F00u,
  0x03FFFFFFu,
  0x1u,0x1u,0x1u,0x1u,0x1u,0x1u
};

// packed f32x2 -> bf16x2 (RNE) via native cvt
__device__ __forceinline__ u32 pk2(float a, float b) {
  float2 f; f.x = a; f.y = b;
  __hip_bfloat162 h = __float22bfloat162_rn(f);
  union { __hip_bfloat162 h; u32 u; } c; c.h = h; return c.u;
}
__device__ __forceinline__ uint2 pk4(float a, float b, float c, float d) {
  uint2 r; r.x = pk2(a, b); r.y = pk2(c, d); return r;
}
// bijective 64B-row swizzle: XOR on the FULL byte offset (round-3-verified)
__device__ __forceinline__ u32 sw64(int row, int col2) {
  return (u32)((row * 64 + col2) ^ ((row & 7) << 4));
}
// async global->LDS, 16B per lane; LDS dest = uniform base + lane*16 (HW rule)
__device__ __forceinline__ void gll16(const void* g, void* l) {
  __builtin_amdgcn_global_load_lds(
      (const __attribute__((address_space(1))) void*)g,
      (__attribute__((address_space(3))) void*)l, 16, 0, 0);
}

// ---- prep: fragment-order bf16 weight images + packed bias ----
__global__ __launch_bounds__(256)
void prep(const float* __restrict__ qkv_w, const float* __restrict__ qkv_b,
          const float* __restrict__ out_w, unsigned char* __restrict__ ws)
{
  int t = blockIdx.x * 256 + threadIdx.x;
  if (t < 24576) {                       // qkv frags: 8h x 48fr x 64 lanes
    int h = t / 3072, rem = t - h * 3072;
    int fr = rem >> 6, ln = rem & 63;
    int ct = fr >> 3, ks = fr & 7;
    int lr = ln & 15, lg = ln >> 4;
    int fg = (ct >> 1) * 256 + h * 32 + (ct & 1) * 16 + lr;
    const float* s = qkv_w + fg * 256 + ks * 32 + lg * 8;
    float4 v0 = *(const float4*)s, v1 = *(const float4*)(s + 4);
    uint4 o;
    o.x = pk2(v0.x, v0.y); o.y = pk2(v0.z, v0.w);
    o.z = pk2(v1.x, v1.y); o.w = pk2(v1.z, v1.w);
    *(uint4*)(ws + WS_QKVW + (u32)h * 49152u + (u32)fr * 1024u + (u32)ln * 16u) = o;
  } else if (t < 32768) {                // outw frags: 128fr x 64 lanes
    int g = t - 24576;
    int fr = g >> 6, ln = g & 63;
    int ft = fr >> 3, ks = fr & 7;
    int lr = ln & 15, lg = ln >> 4;
    const float* s = out_w + (ft * 16 + lr) * 256 + ks * 32 + lg * 8;
    float4 v0 = *(const float4*)s, v1 = *(const float4*)(s + 4);
    uint4 o;
    o.x = pk2(v0.x, v0.y); o.y = pk2(v0.z, v0.w);
    o.z = pk2(v1.x, v1.y); o.w = pk2(v1.z, v1.w);
    *(uint4*)(ws + WS_OUTW + (u32)fr * 1024u + (u32)ln * 16u) = o;
  } else if (t < 33536) {                // qkv bias [8][96]
    int i = t - 32768;
    int h = i / 96, j = i - h * 96;
    int ct = j >> 4, lr = j & 15;
    ((float*)(ws + WS_QB))[i] = qkv_b[(ct >> 1) * 256 + h * 32 + (ct & 1) * 16 + lr];
  }
}

// 512 threads, 4 waves/EU (128-reg tier), 2 blocks/CU = 16 waves/CU.
__global__ __launch_bounds__(512, 4)
void brain_fused(const float* __restrict__ x,
                 const unsigned char* __restrict__ ws,
                 const float* __restrict__ out_b,
                 float* __restrict__ out)
{
  __shared__ char smem[LDS_BYTES] __attribute__((aligned(16)));
  const int tid  = threadIdx.x;
  const int lane = tid & 63;
  const int wid  = tid >> 6;          // 0..7
  const int half = wid & 1;           // 16-row half of the batch
  const int pair = wid >> 1;          // 0..3 = batch within block
  const int lr   = lane & 15;
  const int lg   = lane >> 4;
  const size_t rb = (size_t)blockIdx.x * 104 + (size_t)pair * 26;
  const f32x4 zero = {0.f, 0.f, 0.f, 0.f};
  const u32 pb = LDS_SCR + (u32)pair * 6144u;
  const u32 ob = pb + (u32)half * 1024u;  // own q/P'/ctx' [16][32] bf16
  const u32 kb = pb + 2048u;              // shared k  [32][32]
  const u32 vb = pb + 4096u;              // shared v' [32][32] ([d][s])

  // ---- issue W(0) staging first: DMA overlaps the x-load below ----
#pragma unroll
  for (int i = 0; i < 6; ++i) {
    u32 off = (u32)(wid * 6 + i) * 1024u;
    gll16(ws + WS_QKVW + off + (u32)lane * 16u, smem + LDS_W + off);
  }

  // ---- x A-fragments: this wave's 16 rows; pad rows (>=26) = 0 ----
  const int srow = half * 16 + lr;
  bf16x8 af[8];
  {
    const float* xp = x + (rb + (size_t)srow) * 256;
#pragma unroll
    for (int ks = 0; ks < 8; ++ks) {
      if (srow < 26) {
        const float* p = xp + ks * 32 + lg * 8;
        float4 v0 = *(const float4*)p, v1 = *(const float4*)(p + 4);
        union { u32 u[4]; bf16x8 v; } tt;
        tt.u[0] = pk2(v0.x, v0.y); tt.u[1] = pk2(v0.z, v0.w);
        tt.u[2] = pk2(v1.x, v1.y); tt.u[3] = pk2(v1.z, v1.w);
        af[ks] = tt.v;
      } else {
        af[ks] = (bf16x8)(short)0;
      }
    }
  }

  const u32 mq = MASK32[srow];        // mask for q column = srow
  const float* qb = (const float*)(ws + WS_QB);

  __syncthreads();  // drains vmcnt -> W(0) ready

  bf16x8 cf[8];                       // ctx frags (A-operand of out-proj)

#pragma unroll
  for (int h = 0; h < 8; ++h) {
    // ---- QKV in 3 passes (q, k, v'): 16 rows x 32 feats each, K=256 ----
    // q/k use d-interleaved layout: pos(d) = (d&15)*4 + (d>>4)*2 bytes.
    // Same K-permutation on q and k => QK^T invariant; single b32 write/pair.
#pragma unroll
    for (int p = 0; p < 3; ++p) {
      f32x4 acc[2];
#pragma unroll
      for (int c = 0; c < 2; ++c) {
        float bb = qb[h * 96 + (p * 2 + c) * 16 + lr];
        f32x4 bv = {bb, bb, bb, bb};
        acc[c] = bv;
      }
      __builtin_amdgcn_s_setprio(1);
#pragma unroll
      for (int ks = 0; ks < 8; ++ks) {
        bf16x8 bw[2];
#pragma unroll
        for (int c = 0; c < 2; ++c)
          bw[c] = *(const bf16x8*)(smem + LDS_W + (u32)(((p * 2 + c) * 8 + ks) << 10) + (u32)lane * 16u);
#pragma unroll
        for (int c = 0; c < 2; ++c)
          acc[c] = __builtin_amdgcn_mfma_f32_16x16x32_bf16(af[ks], bw[c], acc[c], 0, 0, 0);
      }
      __builtin_amdgcn_s_setprio(0);
      // per-pass scratch write
      if (p == 0) {
#pragma unroll
        for (int r = 0; r < 4; ++r)
          *(u32*)(smem + ob + sw64(lg * 4 + r, lr * 4)) = pk2(acc[0][r], acc[1][r]);
      } else if (p == 1) {
#pragma unroll
        for (int r = 0; r < 4; ++r)
          *(u32*)(smem + kb + sw64(half * 16 + lg * 4 + r, lr * 4)) = pk2(acc[0][r], acc[1][r]);
      } else {
#pragma unroll
        for (int c = 0; c < 2; ++c)
          *(uint2*)(smem + vb + sw64(c * 16 + lr, (half * 16 + lg * 4) * 2)) =
              pk4(acc[c][0], acc[c][1], acc[c][2], acc[c][3]);
      }
    }
    __syncthreads();  // b2: pair k/v' visible AND all waves done reading W(h)

    // ---- async stage of next LDS image overlaps the attention below ----
    if (h < 7) {
      const unsigned char* nsrc = ws + WS_QKVW + (u32)(h + 1) * 49152u;
#pragma unroll
      for (int i = 0; i < 6; ++i) {
        u32 off = (u32)(wid * 6 + i) * 1024u;
        gll16(nsrc + off + (u32)lane * 16u, smem + LDS_W + off);
      }
    } else {
      // out-proj chunk 0 -> buf0 [0,32K)
#pragma unroll
      for (int i = 0; i < 4; ++i) {
        u32 off = (u32)(wid * 4 + i) * 1024u;
        gll16(ws + WS_OUTW + off + (u32)lane * 16u, smem + off);
      }
    }

    // ---- QK^T: sc = K(32) x Q(own 16); both frags read the interleaved d ----
    bf16x8 qf = *(const bf16x8*)(smem + ob + sw64(lr, lg * 16));
    bf16x8 kf[2];
#pragma unroll
    for (int t = 0; t < 2; ++t)
      kf[t] = *(const bf16x8*)(smem + kb + sw64(t * 16 + lr, lg * 16));
    f32x4 sc[2];
    __builtin_amdgcn_s_setprio(1);
#pragma unroll
    for (int st = 0; st < 2; ++st)
      sc[st] = __builtin_amdgcn_mfma_f32_16x16x32_bf16(kf[st], qf, zero, 0, 0, 0);
    __builtin_amdgcn_s_setprio(0);

    // ---- masked softmax (q col = srow), P'[q_loc][s_k] packed b64 ----
    // mask applied ONCE: t = bit ? sc : -3e38; reused for max tree and exp
    // (exp of (-3e38 - mx)*c underflows to +0 => masked prob = 0).
    {
      float t[2][4];
      float mx = -3.0e38f;
#pragma unroll
      for (int st = 0; st < 2; ++st)
#pragma unroll
        for (int r = 0; r < 4; ++r) {
          int sk = st * 16 + lg * 4 + r;
          t[st][r] = ((mq >> sk) & 1u) ? sc[st][r] : -3.0e38f;
          mx = fmaxf(mx, t[st][r]);
        }
      mx = fmaxf(mx, __shfl_xor(mx, 16));
      mx = fmaxf(mx, __shfl_xor(mx, 32));
      float sum = 0.f;
#pragma unroll
      for (int st = 0; st < 2; ++st)
#pragma unroll
        for (int r = 0; r < 4; ++r) {
          // exp(s/sqrt(32)): native v_exp via __expf (1 mul + exp)
          float p = __expf((t[st][r] - mx) * 0.17677670f);
          t[st][r] = p; sum += p;
        }
      sum += __shfl_xor(sum, 16);
      sum += __shfl_xor(sum, 32);
      float ri = __builtin_amdgcn_rcpf(sum);
#pragma unroll
      for (int st = 0; st < 2; ++st)
        *(uint2*)(smem + ob + sw64(lr, (st * 16 + lg * 4) * 2)) =
            pk4(t[st][0] * ri, t[st][1] * ri, t[st][2] * ri, t[st][3] * ri);
    }

    // ---- PV: ctx^T = V'(32d) x P'(own 16q) ----
    bf16x8 vf[2];
#pragma unroll
    for (int t = 0; t < 2; ++t)
      vf[t] = *(const bf16x8*)(smem + vb + sw64(t * 16 + lr, lg * 16));
    bf16x8 pf = *(const bf16x8*)(smem + ob + sw64(lr, lg * 16));
    f32x4 pv[2];
    __builtin_amdgcn_s_setprio(1);
#pragma unroll
    for (int dt = 0; dt < 2; ++dt)
      pv[dt] = __builtin_amdgcn_mfma_f32_16x16x32_bf16(vf[dt], pf, zero, 0, 0, 0);
    __builtin_amdgcn_s_setprio(0);

    // ctx'[q_loc][d] packed b64, then read ctx frag
#pragma unroll
    for (int dt = 0; dt < 2; ++dt)
      *(uint2*)(smem + ob + sw64(lr, (dt * 16 + lg * 4) * 2)) =
          pk4(pv[dt][0], pv[dt][1], pv[dt][2], pv[dt][3]);
    cf[h] = *(const bf16x8*)(smem + ob + sw64(lr, lg * 16));

    __syncthreads();  // b3: drains staging vmcnt; scratch free for next head
  } // heads

  // ---- out-projection: 4 chunks of 64 cols, LDS double-buffered ----
  // buf0 = [0,32K), buf1 = [32K,64K) (old W tail + scratch; dead after b3).
  // 1 barrier per chunk; next-chunk gll16 overlaps current MFMAs.
#pragma unroll
  for (int fc = 0; fc < 4; ++fc) {
    const u32 cur = (fc & 1) ? 32768u : 0u;
    if (fc < 3) {
      const u32 nxt = ((fc + 1) & 1) ? 32768u : 0u;
#pragma unroll
      for (int i = 0; i < 4; ++i) {
        u32 off = (u32)(wid * 4 + i) * 1024u;
        gll16(ws + WS_OUTW + (u32)(fc + 1) * 32768u + off + (u32)lane * 16u,
              smem + nxt + off);
      }
    }
    f32x4 oa[4];
#pragma unroll
    for (int j = 0; j < 4; ++j) {
      float bo = out_b[(fc * 4 + j) * 16 + lr];
      f32x4 bv = {bo, bo, bo, bo};
      oa[j] = bv;
    }
    __builtin_amdgcn_s_setprio(1);
#pragma unroll
    for (int ks = 0; ks < 8; ++ks) {
      bf16x8 bw[4];
#pragma unroll
      for (int j = 0; j < 4; ++j)
        bw[j] = *(const bf16x8*)(smem + cur + (u32)((j * 8 + ks) << 10) + (u32)lane * 16u);
#pragma unroll
      for (int j = 0; j < 4; ++j)
        oa[j] = __builtin_amdgcn_mfma_f32_16x16x32_bf16(cf[ks], bw[j], oa[j], 0, 0, 0);
    }
    __builtin_amdgcn_s_setprio(0);
#pragma unroll
    for (int j = 0; j < 4; ++j)
#pragma unroll
      for (int r = 0; r < 4; ++r) {
        int qrow = half * 16 + lg * 4 + r;
        if (qrow < 26)
          out[(rb + (size_t)qrow) * 256 + (fc * 4 + j) * 16 + lr] = oa[j][r];
      }
    if (fc < 3)
      __syncthreads();  // drains next-chunk gll16; all waves done with cur
  }
}

extern "C" void kernel_launch(void* const* d_in, const int* in_sizes, int n_in,
                              void* d_out, int out_size, void* d_ws, size_t ws_size,
                              hipStream_t stream) {
  (void)in_sizes; (void)n_in; (void)out_size; (void)ws_size;
  const float* x     = (const float*)d_in[0];
  const float* qkv_w = (const float*)d_in[1];
  const float* qkv_b = (const float*)d_in[2];
  const float* out_w = (const float*)d_in[3];
  const float* out_b = (const float*)d_in[4];
  unsigned char* ws = (unsigned char*)d_ws;
  float* out = (float*)d_out;

  prep<<<dim3(131), dim3(256), 0, stream>>>(qkv_w, qkv_b, out_w, ws);
  brain_fused<<<dim3(4096), dim3(512), 0, stream>>>(x, ws, out_b, out);
}

// Round 17
// 421.749 us; speedup vs baseline: 1.1174x; 1.0024x over previous
//
#include <hip/hip_runtime.h>
#include <hip/hip_bf16.h>

typedef short bf16x8 __attribute__((ext_vector_type(8)));
typedef float f32x4  __attribute__((ext_vector_type(4)));
typedef unsigned short u16;
typedef unsigned int u32;

// ---- LDS: W frag-image 48KB + 4 pairs x 6KB scratch = 72KB (2 blocks/CU) ----
// out-proj reuses [0,32K) and [32K,64K) as a double buffer (scratch dead then).
#define LDS_W     0u
#define LDS_SCR   49152u
#define LDS_BYTES 73728u

// ---- workspace ----
#define WS_QKVW 0u          // 8 heads x 48 frags x 1KB  (frag = (ct*8+ks)*1024 + lane*16)
#define WS_OUTW 393216u     // 128 frags x 1KB = 4 chunks x 32KB
#define WS_QB   524288u     // [8][96] f32

// mask rows (bits 0..25); rows 26..31 dummy bit0 keeps pad rows finite
__constant__ u32 MASK32[32] = {
  0x0210000Fu,0x0210000Fu,0x0210000Fu,0x0210000Fu,
  0x026000F0u,0x026000F0u,0x026000F0u,0x026000F0u,
  0x03800F00u,0x03800F00u,0x03800F00u,0x03800F00u,
  0x0200F000u,0x0200F000u,0x0200F000u,0x0200F000u,
  0x020F0000u,0x020F0000u,0x020F0000u,0x020F0000u,
  0x0210000Fu,
  0x026000F0u,0x026000F0u,
  0x03800F00u,0x03800F00u,
  0x03FFFFFFu,
  0x1u,0x1u,0x1u,0x1u,0x1u,0x1u
};

// packed f32x2 -> bf16x2 (RNE) via native cvt
__device__ __forceinline__ u32 pk2(float a, float b) {
  float2 f; f.x = a; f.y = b;
  __hip_bfloat162 h = __float22bfloat162_rn(f);
  union { __hip_bfloat162 h; u32 u; } c; c.h = h; return c.u;
}
__device__ __forceinline__ uint2 pk4(float a, float b, float c, float d) {
  uint2 r; r.x = pk2(a, b); r.y = pk2(c, d); return r;
}
// bijective 64B-row swizzle: XOR on the FULL byte offset (round-3-verified)
__device__ __forceinline__ u32 sw64(int row, int col2) {
  return (u32)((row * 64 + col2) ^ ((row & 7) << 4));
}
// async global->LDS, 16B per lane; LDS dest = uniform base + lane*16 (HW rule)
__device__ __forceinline__ void gll16(const void* g, void* l) {
  __builtin_amdgcn_global_load_lds(
      (const __attribute__((address_space(1))) void*)g,
      (__attribute__((address_space(3))) void*)l, 16, 0, 0);
}

// ---- prep: fragment-order bf16 weight images + packed bias ----
__global__ __launch_bounds__(256)
void prep(const float* __restrict__ qkv_w, const float* __restrict__ qkv_b,
          const float* __restrict__ out_w, unsigned char* __restrict__ ws)
{
  int t = blockIdx.x * 256 + threadIdx.x;
  if (t < 24576) {                       // qkv frags: 8h x 48fr x 64 lanes
    int h = t / 3072, rem = t - h * 3072;
    int fr = rem >> 6, ln = rem & 63;
    int ct = fr >> 3, ks = fr & 7;
    int lr = ln & 15, lg = ln >> 4;
    int fg = (ct >> 1) * 256 + h * 32 + (ct & 1) * 16 + lr;
    const float* s = qkv_w + fg * 256 + ks * 32 + lg * 8;
    float4 v0 = *(const float4*)s, v1 = *(const float4*)(s + 4);
    uint4 o;
    o.x = pk2(v0.x, v0.y); o.y = pk2(v0.z, v0.w);
    o.z = pk2(v1.x, v1.y); o.w = pk2(v1.z, v1.w);
    *(uint4*)(ws + WS_QKVW + (u32)h * 49152u + (u32)fr * 1024u + (u32)ln * 16u) = o;
  } else if (t < 32768) {                // outw frags: 128fr x 64 lanes
    int g = t - 24576;
    int fr = g >> 6, ln = g & 63;
    int ft = fr >> 3, ks = fr & 7;
    int lr = ln & 15, lg = ln >> 4;
    const float* s = out_w + (ft * 16 + lr) * 256 + ks * 32 + lg * 8;
    float4 v0 = *(const float4*)s, v1 = *(const float4*)(s + 4);
    uint4 o;
    o.x = pk2(v0.x, v0.y); o.y = pk2(v0.z, v0.w);
    o.z = pk2(v1.x, v1.y); o.w = pk2(v1.z, v1.w);
    *(uint4*)(ws + WS_OUTW + (u32)fr * 1024u + (u32)ln * 16u) = o;
  } else if (t < 33536) {                // qkv bias [8][96]
    int i = t - 32768;
    int h = i / 96, j = i - h * 96;
    int ct = j >> 4, lr = j & 15;
    ((float*)(ws + WS_QB))[i] = qkv_b[(ct >> 1) * 256 + h * 32 + (ct & 1) * 16 + lr];
  }
}

// 512 threads, 4 waves/EU (128-reg tier), 2 blocks/CU = 16 waves/CU.
__global__ __launch_bounds__(512, 4)
void brain_fused(const float* __restrict__ x,
                 const unsigned char* __restrict__ ws,
                 const float* __restrict__ out_b,
                 float* __restrict__ out)
{
  __shared__ char smem[LDS_BYTES] __attribute__((aligned(16)));
  const int tid  = threadIdx.x;
  const int lane = tid & 63;
  const int wid  = tid >> 6;          // 0..7
  const int half = wid & 1;           // 16-row half of the batch
  const int pair = wid >> 1;          // 0..3 = batch within block
  const int lr   = lane & 15;
  const int lg   = lane >> 4;
  const size_t rb = (size_t)blockIdx.x * 104 + (size_t)pair * 26;
  const f32x4 zero = {0.f, 0.f, 0.f, 0.f};
  const u32 pb = LDS_SCR + (u32)pair * 6144u;
  const u32 ob = pb + (u32)half * 1024u;  // own q/P'/ctx' [16][32] bf16
  const u32 kb = pb + 2048u;              // shared k  [32][32]
  const u32 vb = pb + 4096u;              // shared v' [32][32] ([d][s])

  // ---- issue W(0) staging first: DMA overlaps the x-load below ----
#pragma unroll
  for (int i = 0; i < 6; ++i) {
    u32 off = (u32)(wid * 6 + i) * 1024u;
    gll16(ws + WS_QKVW + off + (u32)lane * 16u, smem + LDS_W + off);
  }

  // ---- x A-fragments: this wave's 16 rows; pad rows (>=26) = 0 ----
  const int srow = half * 16 + lr;
  bf16x8 af[8];
  {
    const float* xp = x + (rb + (size_t)srow) * 256;
#pragma unroll
    for (int ks = 0; ks < 8; ++ks) {
      if (srow < 26) {
        const float* p = xp + ks * 32 + lg * 8;
        float4 v0 = *(const float4*)p, v1 = *(const float4*)(p + 4);
        union { u32 u[4]; bf16x8 v; } tt;
        tt.u[0] = pk2(v0.x, v0.y); tt.u[1] = pk2(v0.z, v0.w);
        tt.u[2] = pk2(v1.x, v1.y); tt.u[3] = pk2(v1.z, v1.w);
        af[ks] = tt.v;
      } else {
        af[ks] = (bf16x8)(short)0;
      }
    }
  }

  const u32 mq = MASK32[srow];        // mask for q column = srow
  const float* qb = (const float*)(ws + WS_QB);

  __syncthreads();  // drains vmcnt -> W(0) ready

  bf16x8 cf[8];                       // ctx frags (A-operand of out-proj)

#pragma unroll
  for (int h = 0; h < 8; ++h) {
    // ---- QKV in 3 passes (q, k, v'): 16 rows x 32 feats each, K=256 ----
    // q/k use d-interleaved layout: pos(d) = (d&15)*4 + (d>>4)*2 bytes.
    // Same K-permutation on q and k => QK^T invariant; single b32 write/pair.
#pragma unroll
    for (int p = 0; p < 3; ++p) {
      f32x4 acc[2];
#pragma unroll
      for (int c = 0; c < 2; ++c) {
        float bb = qb[h * 96 + (p * 2 + c) * 16 + lr];
        f32x4 bv = {bb, bb, bb, bb};
        acc[c] = bv;
      }
      __builtin_amdgcn_s_setprio(1);
#pragma unroll
      for (int ks = 0; ks < 8; ++ks) {
        bf16x8 bw[2];
#pragma unroll
        for (int c = 0; c < 2; ++c)
          bw[c] = *(const bf16x8*)(smem + LDS_W + (u32)(((p * 2 + c) * 8 + ks) << 10) + (u32)lane * 16u);
#pragma unroll
        for (int c = 0; c < 2; ++c)
          acc[c] = __builtin_amdgcn_mfma_f32_16x16x32_bf16(af[ks], bw[c], acc[c], 0, 0, 0);
      }
      __builtin_amdgcn_s_setprio(0);
      // per-pass scratch write
      if (p == 0) {
#pragma unroll
        for (int r = 0; r < 4; ++r)
          *(u32*)(smem + ob + sw64(lg * 4 + r, lr * 4)) = pk2(acc[0][r], acc[1][r]);
      } else if (p == 1) {
#pragma unroll
        for (int r = 0; r < 4; ++r)
          *(u32*)(smem + kb + sw64(half * 16 + lg * 4 + r, lr * 4)) = pk2(acc[0][r], acc[1][r]);
      } else {
#pragma unroll
        for (int c = 0; c < 2; ++c)
          *(uint2*)(smem + vb + sw64(c * 16 + lr, (half * 16 + lg * 4) * 2)) =
              pk4(acc[c][0], acc[c][1], acc[c][2], acc[c][3]);
      }
    }
    __syncthreads();  // b2: pair k/v' visible AND all waves done reading W(h)

    // ---- async stage of next LDS image overlaps the attention below ----
    if (h < 7) {
      const unsigned char* nsrc = ws + WS_QKVW + (u32)(h + 1) * 49152u;
#pragma unroll
      for (int i = 0; i < 6; ++i) {
        u32 off = (u32)(wid * 6 + i) * 1024u;
        gll16(nsrc + off + (u32)lane * 16u, smem + LDS_W + off);
      }
    } else {
      // out-proj chunk 0 -> buf0 [0,32K)
#pragma unroll
      for (int i = 0; i < 4; ++i) {
        u32 off = (u32)(wid * 4 + i) * 1024u;
        gll16(ws + WS_OUTW + off + (u32)lane * 16u, smem + off);
      }
    }

    // ---- QK^T: sc = K(32) x Q(own 16); both frags read the interleaved d ----
    bf16x8 qf = *(const bf16x8*)(smem + ob + sw64(lr, lg * 16));
    bf16x8 kf[2];
#pragma unroll
    for (int t = 0; t < 2; ++t)
      kf[t] = *(const bf16x8*)(smem + kb + sw64(t * 16 + lr, lg * 16));
    f32x4 sc[2];
    __builtin_amdgcn_s_setprio(1);
#pragma unroll
    for (int st = 0; st < 2; ++st)
      sc[st] = __builtin_amdgcn_mfma_f32_16x16x32_bf16(kf[st], qf, zero, 0, 0, 0);
    __builtin_amdgcn_s_setprio(0);

    // ---- masked softmax (q col = srow), P'[q_loc][s_k] packed b64 ----
    // mask applied ONCE: t = bit ? sc : -3e38; reused for max tree and exp
    // (exp of (-3e38 - mx)*c underflows to +0 => masked prob = 0).
    {
      float t[2][4];
      float mx = -3.0e38f;
#pragma unroll
      for (int st = 0; st < 2; ++st)
#pragma unroll
        for (int r = 0; r < 4; ++r) {
          int sk = st * 16 + lg * 4 + r;
          t[st][r] = ((mq >> sk) & 1u) ? sc[st][r] : -3.0e38f;
          mx = fmaxf(mx, t[st][r]);
        }
      mx = fmaxf(mx, __shfl_xor(mx, 16));
      mx = fmaxf(mx, __shfl_xor(mx, 32));
      float sum = 0.f;
#pragma unroll
      for (int st = 0; st < 2; ++st)
#pragma unroll
        for (int r = 0; r < 4; ++r) {
          // exp(s/sqrt(32)): native v_exp via __expf (1 mul + exp)
          float p = __expf((t[st][r] - mx) * 0.17677670f);
          t[st][r] = p; sum += p;
        }
      sum += __shfl_xor(sum, 16);
      sum += __shfl_xor(sum, 32);
      float ri = __builtin_amdgcn_rcpf(sum);
#pragma unroll
      for (int st = 0; st < 2; ++st)
        *(uint2*)(smem + ob + sw64(lr, (st * 16 + lg * 4) * 2)) =
            pk4(t[st][0] * ri, t[st][1] * ri, t[st][2] * ri, t[st][3] * ri);
    }

    // ---- PV: ctx^T = V'(32d) x P'(own 16q) ----
    bf16x8 vf[2];
#pragma unroll
    for (int t = 0; t < 2; ++t)
      vf[t] = *(const bf16x8*)(smem + vb + sw64(t * 16 + lr, lg * 16));
    bf16x8 pf = *(const bf16x8*)(smem + ob + sw64(lr, lg * 16));
    f32x4 pv[2];
    __builtin_amdgcn_s_setprio(1);
#pragma unroll
    for (int dt = 0; dt < 2; ++dt)
      pv[dt] = __builtin_amdgcn_mfma_f32_16x16x32_bf16(vf[dt], pf, zero, 0, 0, 0);
    __builtin_amdgcn_s_setprio(0);

    // ctx'[q_loc][d] packed b64, then read ctx frag
#pragma unroll
    for (int dt = 0; dt < 2; ++dt)
      *(uint2*)(smem + ob + sw64(lr, (dt * 16 + lg * 4) * 2)) =
          pk4(pv[dt][0], pv[dt][1], pv[dt][2], pv[dt][3]);
    cf[h] = *(const bf16x8*)(smem + ob + sw64(lr, lg * 16));

    __syncthreads();  // b3: drains staging vmcnt; scratch free for next head
  } // heads

  // ---- out-projection: 4 chunks of 64 cols, LDS double-buffered ----
  // buf0 = [0,32K), buf1 = [32K,64K) (old W tail + scratch; dead after b3).
  // 1 barrier per chunk; next-chunk gll16 overlaps current MFMAs.
#pragma unroll
  for (int fc = 0; fc < 4; ++fc) {
    const u32 cur = (fc & 1) ? 32768u : 0u;
    if (fc < 3) {
      const u32 nxt = ((fc + 1) & 1) ? 32768u : 0u;
#pragma unroll
      for (int i = 0; i < 4; ++i) {
        u32 off = (u32)(wid * 4 + i) * 1024u;
        gll16(ws + WS_OUTW + (u32)(fc + 1) * 32768u + off + (u32)lane * 16u,
              smem + nxt + off);
      }
    }
    f32x4 oa[4];
#pragma unroll
    for (int j = 0; j < 4; ++j) {
      float bo = out_b[(fc * 4 + j) * 16 + lr];
      f32x4 bv = {bo, bo, bo, bo};
      oa[j] = bv;
    }
    __builtin_amdgcn_s_setprio(1);
#pragma unroll
    for (int ks = 0; ks < 8; ++ks) {
      bf16x8 bw[4];
#pragma unroll
      for (int j = 0; j < 4; ++j)
        bw[j] = *(const bf16x8*)(smem + cur + (u32)((j * 8 + ks) << 10) + (u32)lane * 16u);
#pragma unroll
      for (int j = 0; j < 4; ++j)
        oa[j] = __builtin_amdgcn_mfma_f32_16x16x32_bf16(cf[ks], bw[j], oa[j], 0, 0, 0);
    }
    __builtin_amdgcn_s_setprio(0);
#pragma unroll
    for (int j = 0; j < 4; ++j)
#pragma unroll
      for (int r = 0; r < 4; ++r) {
        int qrow = half * 16 + lg * 4 + r;
        if (qrow < 26)
          out[(rb + (size_t)qrow) * 256 + (fc * 4 + j) * 16 + lr] = oa[j][r];
      }
    if (fc < 3)
      __syncthreads();  // drains next-chunk gll16; all waves done with cur
  }
}

extern "C" void kernel_launch(void* const* d_in, const int* in_sizes, int n_in,
                              void* d_out, int out_size, void* d_ws, size_t ws_size,
                              hipStream_t stream) {
  (void)in_sizes; (void)n_in; (void)out_size; (void)ws_size;
  const float* x     = (const float*)d_in[0];
  const float* qkv_w = (const float*)d_in[1];
  const float* qkv_b = (const float*)d_in[2];
  const float* out_w = (const float*)d_in[3];
  const float* out_b = (const float*)d_in[4];
  unsigned char* ws = (unsigned char*)d_ws;
  float* out = (float*)d_out;

  prep<<<dim3(131), dim3(256), 0, stream>>>(qkv_w, qkv_b, out_w, ws);
  brain_fused<<<dim3(4096), dim3(512), 0, stream>>>(x, ws, out_b, out);
}